// Round 8
// baseline (139.174 us; speedup 1.0000x reference)
//
#include <hip/hip_runtime.h>

// B=8, T=2048, D_MODEL=1024, D_HEAD=64, fp32 in/out.
// pack  -> Wt bf16[192][1024]
// gemm  -> qkvqk bf16[16384][128] (Q log2-scaled | K), vT bf16[8][64][2048]
//          R17: BK=256 -> 1 KB contiguous per-row A segments (HBM page efficiency;
//          R15's 256B segments were worse, R16's occupancy was neutral -> granularity
//          is the lever). N-split 96 cols, LDS 80 KB, 2 blocks/CU, 4 drains.
// attn  -> split-K no-max log2 flash; 128-row q-supertile x 128-key chunk (R13).
//          512 thr/block, waves 0-3 = q-tile A, waves 4-7 = q-tile B concurrent.
// combine -> weight-1 merge of <=16 chunks per (b, 64-row q-tile)
#define TT   2048
#define DM   1024
#define DH   64
#define NB   8
#define BK   256   // gemm K-tile: 1 KB/row A segments, 4 barrier-drains
#define KST  72    // p_lds row stride (elems)

typedef __attribute__((ext_vector_type(4))) float          f32x4;
typedef __attribute__((ext_vector_type(4))) int            i32x4;
typedef __attribute__((ext_vector_type(4))) unsigned short u16x4;
typedef __attribute__((ext_vector_type(8))) short          s16x8;  // bf16x8 frag (4 VGPRs)

__device__ __forceinline__ unsigned short f2bf(float f) {  // RNE fp32->bf16
  unsigned int u = __float_as_uint(f);
  u += 0x7fffu + ((u >> 16) & 1u);
  return (unsigned short)(u >> 16);
}

#define MFMA(acc, a, b) \
  (acc) = __builtin_amdgcn_mfma_f32_16x16x32_bf16((a), (b), (acc), 0, 0, 0)

// Async global->LDS DMA, 16B/lane. LDS dest is wave-uniform base + lane*16.
__device__ __forceinline__ void gload_lds16(const void* g, void* l) {
  __builtin_amdgcn_global_load_lds(
      (const __attribute__((address_space(1))) void*)g,
      (__attribute__((address_space(3))) void*)l, 16, 0, 0);
}

// ws layout (bytes)
#define WS_WT    0u
#define WS_QK    393216u     // 16384*128*2 = 4,194,304
#define WS_VT    4587520u    // 8*64*2048*2 = 2,097,152
#define WS_OP    6684672u    // 8*272*4096*2 = 17,825,792 (bf16 partial O)
#define WS_ML    24510464u   // 8*272*64*4   = 557,056    (f32 l per row)

// ---------------- pack: W_Q|W_K|W_V fp32[1024][64] -> Wt bf16[192][1024] -------------
__global__ __launch_bounds__(256) void pack_w_kernel(
    const float* __restrict__ wq, const float* __restrict__ wk,
    const float* __restrict__ wv, unsigned short* __restrict__ wt) {
  int idx = blockIdx.x * 256 + threadIdx.x;
  if (idx >= 192 * DM) return;
  int n = idx >> 10;
  int k = idx & (DM - 1);
  const float* src = (n < 64) ? wq : ((n < 128) ? wk : wv);
  wt[(size_t)n * DM + k] = f2bf(src[(size_t)k * DH + (n & 63)]);
}

// ---------------- QKV GEMM (R17: 32x96 tile, BK=256, 2 blocks/CU) --------------------
// 1024 blocks x 256 thr. bid = half*512 + stripe: rows [stripe*32,+32), cols
// [half*96,+96). Per K-step each A row contributes a CONTIGUOUS 1 KB segment (page-
// friendly); 4 vmcnt-drain barriers. half=1 round re-reads A from L3 (64 MB < 256 MB).
// A fp32 + B bf16 staged by global_load_lds into XOR-swizzled LDS (^lsw on read).
__global__ __launch_bounds__(256, 2) void qkv_gemm_kernel(
    const float* __restrict__ x, const unsigned short* __restrict__ wt,
    unsigned short* __restrict__ qkvqk, unsigned short* __restrict__ vt) {
  __shared__ __align__(16) float          a_lds[32 * BK];   // 32 KB, swizzled chunks
  __shared__ __align__(16) unsigned short b_lds[96 * BK];   // 48 KB, swizzled chunks

  const int tid  = threadIdx.x;
  const int lane = tid & 63;
  const int w    = tid >> 6;
  const int ln   = lane & 15;
  const int quad = lane >> 4;
  const int mw   = w & 1;
  const int nw   = w >> 1;          // 0..1 (48-col slice)
  const int bid  = blockIdx.x;      // 0..1023
  const int m0   = (bid & 511) * 32;
  const int half = bid >> 9;        // col half: 0 -> cols 0..95, 1 -> 96..191
  const int n0   = nw * 48;         // local col base
  const int lsw  = ln & 7;          // read-side swizzle key

  // A: 32 rows x 64 chunks (16B = 4 fp32) = 1 KB/row. 2048 slots, 8 DMAs/wave
  // (each DMA = one full row segment).
  int agoff[8];
  #pragma unroll
  for (int i = 0; i < 8; ++i) {
    int s = i * 256 + w * 64 + lane;
    int m = s >> 6, cc = s & 63;
    agoff[i] = (m0 + m) * DM + ((cc ^ (m & 7)) << 2);
  }
  // B: 96 rows x 32 chunks (16B = 8 bf16) = 512 B/row. 3072 slots, 12 DMAs/wave.
  int bgoff[12];
  #pragma unroll
  for (int j = 0; j < 12; ++j) {
    int s = j * 256 + w * 64 + lane;
    int n = s >> 5, cc = s & 31;
    bgoff[j] = (half * 96 + n) * DM + ((cc ^ (n & 7)) << 3);
  }

  f32x4 acc[3];
  #pragma unroll
  for (int i = 0; i < 3; ++i) acc[i] = (f32x4){0.f, 0.f, 0.f, 0.f};
  union { s16x8 v; unsigned short h[8]; } ap;

  // prologue stage of tile 0
  #pragma unroll
  for (int i = 0; i < 8; ++i)
    gload_lds16(x + agoff[i], (void*)(a_lds + (i * 256 + w * 64) * 4));
  #pragma unroll
  for (int j = 0; j < 12; ++j)
    gload_lds16(wt + bgoff[j], (void*)(b_lds + (j * 256 + w * 64) * 8));

  for (int k0 = 0; k0 < DM; k0 += BK) {
    __syncthreads();               // drains vmcnt(0): staged tile visible
    #pragma unroll
    for (int ks = 0; ks < BK; ks += 32) {
      const int m  = mw * 16 + ln;
      const int c0 = (ks >> 2) + 2 * quad;       // float-chunk of A fragment (0..62)
      f32x4 v0 = *(const f32x4*)&a_lds[m * BK + ((c0 ^ lsw) << 2)];
      f32x4 v1 = *(const f32x4*)&a_lds[m * BK + (((c0 + 1) ^ lsw) << 2)];
      #pragma unroll
      for (int j = 0; j < 4; ++j) { ap.h[j] = f2bf(v0[j]); ap.h[4 + j] = f2bf(v1[j]); }
      s16x8 af = ap.v;
      const int cb = (ks >> 3) + quad;           // bf16-chunk of B fragment (0..31)
      #pragma unroll
      for (int nt = 0; nt < 3; ++nt) {
        int nl = n0 + nt * 16 + ln;              // nl & 7 == ln & 7 (48,16 = 0 mod 8)
        s16x8 bf = *(const s16x8*)&b_lds[nl * BK + ((cb ^ lsw) << 3)];
        MFMA(acc[nt], af, bf);
      }
    }
    __syncthreads();               // all waves done reading before re-stage
    if (k0 + BK < DM) {
      const int kn = k0 + BK;
      #pragma unroll
      for (int i = 0; i < 8; ++i)
        gload_lds16(x + agoff[i] + kn, (void*)(a_lds + (i * 256 + w * 64) * 4));
      #pragma unroll
      for (int j = 0; j < 12; ++j)
        gload_lds16(wt + bgoff[j] + kn, (void*)(b_lds + (j * 256 + w * 64) * 8));
    }
  }

  const float QS = 0.18033688011112042f;  // (1/8) * log2(e)
  const int mm0 = m0 + mw * 16;
  const int bz  = mm0 >> 11;
  const int tb  = (mm0 & 2047) + quad * 4;
  #pragma unroll
  for (int nt = 0; nt < 3; ++nt) {
    const int ncol = half * 96 + n0 + nt * 16 + ln;
    if (ncol < 128) {                     // Q (scaled) | K -> qkvqk
      const float sc = (ncol < 64) ? QS : 1.0f;
      #pragma unroll
      for (int r = 0; r < 4; ++r) {
        int row = mm0 + quad * 4 + r;     // C/D: row = quad*4+reg, col = lane&15
        qkvqk[(size_t)row * 128 + ncol] = f2bf(acc[nt][r] * sc);
      }
    } else {                              // V -> vT[b][d][t]
      int d = ncol - 128;
      u16x4 h;
      #pragma unroll
      for (int r = 0; r < 4; ++r) h[r] = f2bf(acc[nt][r]);
      *(u16x4*)(vt + ((size_t)bz * 64 + d) * TT + tb) = h;
    }
  }
}

// ---------------- attn partial: 128-row q-supertile x 128-key chunk (R13) ------------
// Per b: supertile s (0..15), chunk c (0..s): Ctab[s]=s(s+1)/2, 136 blocks/b, grid 1088.
// 512 threads: waves 0-3 process q-tile 2s (A), waves 4-7 process q-tile 2s+1 (B),
// concurrently. Group 0 skips key-tile ct=1 when c==s (above diagonal).
// LDS: k 16 KB + v 16 KB + p 2x9 KB = 50 KB -> 3 blocks/CU (24 waves/CU).
__global__ __launch_bounds__(512) void attn_part_kernel(
    const unsigned short* __restrict__ qkvqk, const unsigned short* __restrict__ vt,
    unsigned short* __restrict__ opart, float* __restrict__ ml) {
  const int Ctab[16] = {0,1,3,6,10,15,21,28,36,45,55,66,78,91,105,120};
  const int f  = blockIdx.x;       // 0..1087
  const int bz = f / 136;
  const int rw = f - bz * 136;
  int s = 0;
  #pragma unroll
  for (int t = 1; t < 16; ++t) if (rw >= Ctab[t]) s = t;
  const int c = rw - Ctab[s];      // 0..s

  __shared__ __align__(16) unsigned short k_lds[128 * 64];       // 16 KB, swizzled
  __shared__ __align__(16) unsigned short v_lds[64 * 128];       // 16 KB, swizzled
  __shared__ __align__(16) unsigned short p_lds[2 * 64 * KST];   // 18 KB, padded

  const int tid  = threadIdx.x;
  const int w    = tid >> 6;       // 0..7
  const int grp  = w >> 2;         // 0 = q-tile A (2s), 1 = q-tile B (2s+1)
  const int wq   = w & 3;          // 16-row slice within the 64-row q-tile
  const int lane = tid & 63;
  const int ln   = lane & 15;
  const int quad = lane >> 4;
  const int lsw  = ln & 7;         // read-side swizzle key
  const int bb   = bz * TT;
  const int kbase = c * 128;
  const int qt   = 2 * s + grp;    // this group's q-tile

  // ---- stage K: 128 rows x 8 chunks = 1024 slots, 512 thr -> 2 iters
  #pragma unroll
  for (int i = 0; i < 2; ++i) {
    int base = i * 512 + w * 64;
    int slot = base + lane;
    int row = slot >> 3, cc = slot & 7;
    gload_lds16(qkvqk + (size_t)(bb + kbase + row) * 128 + 64 + ((cc ^ (row & 7)) << 3),
                (void*)(k_lds + base * 8));
  }
  // ---- stage V^T: 64 rows(d) x 16 chunks = 1024 slots
  #pragma unroll
  for (int i = 0; i < 2; ++i) {
    int base = i * 512 + w * 64;
    int slot = base + lane;
    int d = slot >> 4, cc = slot & 15;
    gload_lds16(vt + ((size_t)bz * 64 + d) * TT + kbase + ((cc ^ (d & 7)) << 3),
                (void*)(v_lds + base * 8));
  }

  // Q fragments (log2-scaled already); A-layout m=lane&15, k=quad*8+j
  const unsigned short* qrow = qkvqk + (size_t)(bb + qt * 64 + wq * 16 + ln) * 128;
  const s16x8 qf0 = *(const s16x8*)(qrow + quad * 8);
  const s16x8 qf1 = *(const s16x8*)(qrow + 32 + quad * 8);

  s16x8 ones;
  #pragma unroll
  for (int j = 0; j < 8; ++j) ones[j] = (short)0x3F80;  // bf16 1.0

  f32x4 acc_o[4], acc_l;
  #pragma unroll
  for (int i = 0; i < 4; ++i) acc_o[i] = (f32x4){0.f, 0.f, 0.f, 0.f};
  acc_l = (f32x4){0.f, 0.f, 0.f, 0.f};

  unsigned short* pb = p_lds + grp * 64 * KST;   // group-private P buffer
  const int qg = qt * 64 + wq * 16 + quad * 4;
  __syncthreads();  // drains vmcnt(0): K/V staged

  #pragma unroll
  for (int ct = 0; ct < 2; ++ct) {
    const int ktg = c * 2 + ct;
    if (ktg <= qt) {               // group 0 skips ct=1 when c==s
      const bool diag = (ktg == qt);
      f32x4 acc_s[4];
      #pragma unroll
      for (int i = 0; i < 4; ++i) acc_s[i] = (f32x4){0.f, 0.f, 0.f, 0.f};
      #pragma unroll
      for (int ns = 0; ns < 4; ++ns) {
        const int krow = ct * 64 + ns * 16 + ln;
        s16x8 kf0 = *(const s16x8*)&k_lds[krow * 64 + ((quad ^ lsw) << 3)];
        s16x8 kf1 = *(const s16x8*)&k_lds[krow * 64 + (((4 + quad) ^ lsw) << 3)];
        MFMA(acc_s[ns], qf0, kf0);
        MFMA(acc_s[ns], qf1, kf1);
      }
      #pragma unroll
      for (int r = 0; r < 4; ++r) {
        const int qgr = qg + r;
        #pragma unroll
        for (int ns = 0; ns < 4; ++ns) {
          float sv = acc_s[ns][r];
          if (diag) {
            int kg = ktg * 64 + ns * 16 + ln;
            sv = (kg <= qgr) ? sv : -1e30f;
          }
          pb[(wq * 16 + quad * 4 + r) * KST + ns * 16 + ln] =
              f2bf(__builtin_amdgcn_exp2f(sv));
        }
      }
      #pragma unroll
      for (int kk = 0; kk < 64; kk += 32) {
        s16x8 pf = *(const s16x8*)&pb[(wq * 16 + ln) * KST + kk + quad * 8];
        MFMA(acc_l, pf, ones);
        #pragma unroll
        for (int nt = 0; nt < 4; ++nt) {
          const int d  = nt * 16 + ln;
          const int sc = (ct * 8 + (kk >> 3) + quad) ^ lsw;  // 16 chunks/row, xor low3
          s16x8 vf = *(const s16x8*)&v_lds[d * 128 + sc * 8];
          MFMA(acc_o[nt], pf, vf);
        }
      }
      asm volatile("" ::: "memory");
    }
  }

  // epilogue: slab base per qt: base(2s)=s(s+1), base(2s+1)=(s+1)^2
  const int base = (qt & 1) ? (s + 1) * (s + 1) : s * (s + 1);
  const size_t slab = (size_t)bz * 272 + base + c;
  unsigned short* op = opart + slab * 4096;
  #pragma unroll
  for (int nt = 0; nt < 4; ++nt)
    #pragma unroll
    for (int r = 0; r < 4; ++r)
      op[(wq * 16 + quad * 4 + r) * 64 + nt * 16 + ln] = f2bf(acc_o[nt][r]);
  if (ln == 0) {
    float* lp = ml + slab * 64;
    #pragma unroll
    for (int r = 0; r < 4; ++r)
      lp[wq * 16 + quad * 4 + r] = acc_l[r];
  }
}

// ---------------- combine: weight-1 merge of <=16 chunks -----------------------------
__global__ __launch_bounds__(256) void attn_combine_kernel(
    const unsigned short* __restrict__ opart, const float* __restrict__ ml,
    float* __restrict__ out) {
  const int qt = blockIdx.x;       // 0..31
  const int bz = blockIdx.y;
  const int g  = qt >> 1;
  const int nch = g + 1;           // chunks per q-tile (1..16)
  const int base = (qt & 1) ? (g + 1) * (g + 1) : g * (g + 1);
  const size_t slab0 = (size_t)bz * 272 + base;

  const int tid = threadIdx.x;
  const int row = tid >> 2;
  const int ds  = (tid & 3) * 16;

  float L = 0.f;
  float acc[16];
  #pragma unroll
  for (int j = 0; j < 16; ++j) acc[j] = 0.f;
  #pragma unroll 4
  for (int ch = 0; ch < nch; ++ch) {
    L += ml[(slab0 + ch) * 64 + row];
    const unsigned short* op = opart + (slab0 + ch) * 4096 + row * 64 + ds;
    i32x4 v0 = *(const i32x4*)(op);
    i32x4 v1 = *(const i32x4*)(op + 8);
    #pragma unroll
    for (int j = 0; j < 4; ++j) {
      unsigned int u0 = (unsigned int)v0[j], u1 = (unsigned int)v1[j];
      acc[j * 2]         += __uint_as_float(u0 << 16);
      acc[j * 2 + 1]     += __uint_as_float(u0 & 0xffff0000u);
      acc[8 + j * 2]     += __uint_as_float(u1 << 16);
      acc[8 + j * 2 + 1] += __uint_as_float(u1 & 0xffff0000u);
    }
  }
  float inv = 1.0f / L;
  float* o = out + ((size_t)bz * TT + qt * 64 + row) * 64 + ds;
  #pragma unroll
  for (int j = 0; j < 16; ++j) o[j] = acc[j] * inv;
}

extern "C" void kernel_launch(void* const* d_in, const int* in_sizes, int n_in,
                              void* d_out, int out_size, void* d_ws, size_t ws_size,
                              hipStream_t stream) {
  const float* x  = (const float*)d_in[0];
  const float* wq = (const float*)d_in[1];
  const float* wk = (const float*)d_in[2];
  const float* wv = (const float*)d_in[3];
  float* out = (float*)d_out;

  char* ws = (char*)d_ws;
  unsigned short* wt    = (unsigned short*)(ws + WS_WT);
  unsigned short* qkvqk = (unsigned short*)(ws + WS_QK);
  unsigned short* vt    = (unsigned short*)(ws + WS_VT);
  unsigned short* opart = (unsigned short*)(ws + WS_OP);
  float*          ml    = (float*)(ws + WS_ML);

  pack_w_kernel<<<(192 * DM + 255) / 256, 256, 0, stream>>>(wq, wk, wv, wt);
  qkv_gemm_kernel<<<1024, 256, 0, stream>>>(x, wt, qkvqk, vt);
  attn_part_kernel<<<NB * 136, 512, 0, stream>>>(qkvqk, vt, opart, ml);
  attn_combine_kernel<<<dim3(32, NB), 256, 0, stream>>>(opart, ml, out);
}

// Round 11
// 131.269 us; speedup vs baseline: 1.0602x; 1.0602x over previous
//
#include <hip/hip_runtime.h>

// B=8, T=2048, D_MODEL=1024, D_HEAD=64, fp32 in/out.
// pack  -> Wt bf16[192][1024]
// gemm  -> qkvqk bf16[16384][128] (Q log2-scaled | K), vT bf16[8][64][2048]
//          R13 gemm (BK=128, 32x192, 512 blocks) — best measured; R15/R16/R17
//          alternatives (BK=64/256, N-split occupancy) all neutral-or-worse.
// attn  -> R18: R13 structure + half-tile K/V prefetch. Stage 64-key half 0 ->
//          drain -> issue half 1 -> compute ct=0 (hides half-1 latency) ->
//          drain -> compute ct=1. Waves 0-3 = q-tile 2s, 4-7 = 2s+1 concurrent.
// combine -> weight-1 merge of <=16 chunks per (b, 64-row q-tile)
#define TT   2048
#define DM   1024
#define DH   64
#define NB   8
#define BK   128   // gemm K-tile (8 barrier-drains)
#define KST  72    // p_lds row stride (elems)

typedef __attribute__((ext_vector_type(4))) float          f32x4;
typedef __attribute__((ext_vector_type(4))) int            i32x4;
typedef __attribute__((ext_vector_type(4))) unsigned short u16x4;
typedef __attribute__((ext_vector_type(8))) short          s16x8;  // bf16x8 frag (4 VGPRs)

__device__ __forceinline__ unsigned short f2bf(float f) {  // RNE fp32->bf16
  unsigned int u = __float_as_uint(f);
  u += 0x7fffu + ((u >> 16) & 1u);
  return (unsigned short)(u >> 16);
}

#define MFMA(acc, a, b) \
  (acc) = __builtin_amdgcn_mfma_f32_16x16x32_bf16((a), (b), (acc), 0, 0, 0)

// Async global->LDS DMA, 16B/lane. LDS dest is wave-uniform base + lane*16.
__device__ __forceinline__ void gload_lds16(const void* g, void* l) {
  __builtin_amdgcn_global_load_lds(
      (const __attribute__((address_space(1))) void*)g,
      (__attribute__((address_space(3))) void*)l, 16, 0, 0);
}

// ws layout (bytes)
#define WS_WT    0u
#define WS_QK    393216u     // 16384*128*2 = 4,194,304
#define WS_VT    4587520u    // 8*64*2048*2 = 2,097,152
#define WS_OP    6684672u    // 8*272*4096*2 = 17,825,792 (bf16 partial O)
#define WS_ML    24510464u   // 8*272*64*4   = 557,056    (f32 l per row)

// ---------------- pack: W_Q|W_K|W_V fp32[1024][64] -> Wt bf16[192][1024] -------------
__global__ __launch_bounds__(256) void pack_w_kernel(
    const float* __restrict__ wq, const float* __restrict__ wk,
    const float* __restrict__ wv, unsigned short* __restrict__ wt) {
  int idx = blockIdx.x * 256 + threadIdx.x;
  if (idx >= 192 * DM) return;
  int n = idx >> 10;
  int k = idx & (DM - 1);
  const float* src = (n < 64) ? wq : ((n < 128) ? wk : wv);
  wt[(size_t)n * DM + k] = f2bf(src[(size_t)k * DH + (n & 63)]);
}

// ---------------- QKV GEMM (m97 structure, BK=128) -----------------------------------
// 512 blocks x 256 thr (2 blocks/CU: LDS 64 KB x 2 = 128 <= 160 KB). Block = 32 rows x
// 192 cols, K-step 128 -> 8 vmcnt-drain barriers. A fp32 + B bf16 staged by
// global_load_lds into XOR-swizzled LDS (reads un-swizzle with ^lsw).
__global__ __launch_bounds__(256) void qkv_gemm_kernel(
    const float* __restrict__ x, const unsigned short* __restrict__ wt,
    unsigned short* __restrict__ qkvqk, unsigned short* __restrict__ vt) {
  __shared__ __align__(16) float          a_lds[32 * BK];    // 16 KB, swizzled chunks
  __shared__ __align__(16) unsigned short b_lds[192 * BK];   // 48 KB, swizzled chunks

  const int tid  = threadIdx.x;
  const int lane = tid & 63;
  const int w    = tid >> 6;
  const int ln   = lane & 15;
  const int quad = lane >> 4;
  const int mw   = w & 1;
  const int nw   = w >> 1;
  const int m0   = blockIdx.x * 32;
  const int n0   = nw * 96;
  const int lsw  = ln & 7;          // read-side swizzle key

  // A: 32 rows x 32 chunks (16B = 4 fp32). 1024 slots, 4 DMAs/wave.
  int agoff[4];
  #pragma unroll
  for (int i = 0; i < 4; ++i) {
    int s = i * 256 + w * 64 + lane;
    int m = s >> 5, cc = s & 31;
    agoff[i] = (m0 + m) * DM + ((cc ^ (m & 7)) << 2);
  }
  // B: 192 rows x 16 chunks (16B = 8 bf16). 3072 slots, 12 DMAs/wave.
  int bgoff[12];
  #pragma unroll
  for (int j = 0; j < 12; ++j) {
    int s = j * 256 + w * 64 + lane;
    int n = s >> 4, cc = s & 15;
    bgoff[j] = n * DM + ((cc ^ (n & 7)) << 3);
  }

  f32x4 acc[6];
  #pragma unroll
  for (int i = 0; i < 6; ++i) acc[i] = (f32x4){0.f, 0.f, 0.f, 0.f};
  union { s16x8 v; unsigned short h[8]; } ap;

  // prologue stage of tile 0
  #pragma unroll
  for (int i = 0; i < 4; ++i)
    gload_lds16(x + agoff[i], (void*)(a_lds + (i * 256 + w * 64) * 4));
  #pragma unroll
  for (int j = 0; j < 12; ++j)
    gload_lds16(wt + bgoff[j], (void*)(b_lds + (j * 256 + w * 64) * 8));

  for (int k0 = 0; k0 < DM; k0 += BK) {
    __syncthreads();               // drains vmcnt(0): staged tile visible
    #pragma unroll
    for (int ks = 0; ks < BK; ks += 32) {
      const int m  = mw * 16 + ln;
      const int c0 = (ks >> 2) + 2 * quad;       // float-chunk of A fragment
      f32x4 v0 = *(const f32x4*)&a_lds[m * BK + ((c0 ^ lsw) << 2)];
      f32x4 v1 = *(const f32x4*)&a_lds[m * BK + (((c0 + 1) ^ lsw) << 2)];
      #pragma unroll
      for (int j = 0; j < 4; ++j) { ap.h[j] = f2bf(v0[j]); ap.h[4 + j] = f2bf(v1[j]); }
      s16x8 af = ap.v;
      const int cb = (ks >> 3) + quad;           // bf16-chunk of B fragment
      #pragma unroll
      for (int nt = 0; nt < 6; ++nt) {
        int n = n0 + nt * 16 + ln;
        s16x8 bf = *(const s16x8*)&b_lds[n * BK + ((cb ^ lsw) << 3)];
        MFMA(acc[nt], af, bf);
      }
    }
    __syncthreads();               // all waves done reading before re-stage
    if (k0 + BK < DM) {
      const int kn = k0 + BK;
      #pragma unroll
      for (int i = 0; i < 4; ++i)
        gload_lds16(x + agoff[i] + kn, (void*)(a_lds + (i * 256 + w * 64) * 4));
      #pragma unroll
      for (int j = 0; j < 12; ++j)
        gload_lds16(wt + bgoff[j] + kn, (void*)(b_lds + (j * 256 + w * 64) * 8));
    }
  }

  const float QS = 0.18033688011112042f;  // (1/8) * log2(e)
  const int mm0 = m0 + mw * 16;
  const int bz  = mm0 >> 11;
  const int tb  = (mm0 & 2047) + quad * 4;
  #pragma unroll
  for (int nt = 0; nt < 6; ++nt) {
    const int ncol = n0 + nt * 16 + ln;
    if (ncol < 128) {                     // Q (scaled) | K -> qkvqk
      const float sc = (ncol < 64) ? QS : 1.0f;
      #pragma unroll
      for (int r = 0; r < 4; ++r) {
        int row = mm0 + quad * 4 + r;     // C/D: row = quad*4+reg, col = lane&15
        qkvqk[(size_t)row * 128 + ncol] = f2bf(acc[nt][r] * sc);
      }
    } else {                              // V -> vT[b][d][t]
      int d = ncol - 128;
      u16x4 h;
      #pragma unroll
      for (int r = 0; r < 4; ++r) h[r] = f2bf(acc[nt][r]);
      *(u16x4*)(vt + ((size_t)bz * 64 + d) * TT + tb) = h;
    }
  }
}

// ---------------- attn partial: 128-row q-supertile x 128-key chunk (R18) ------------
// Per b: supertile s (0..15), chunk c (0..s): Ctab[s]=s(s+1)/2, 136 blocks/b, grid 1088.
// 512 threads: waves 0-3 -> q-tile 2s, waves 4-7 -> q-tile 2s+1, concurrent.
// K/V staged in TWO 64-key halves: stage(0) -> drain -> issue stage(1) ->
// compute ct=0 -> drain -> compute ct=1 (half-1 staging hidden under ct=0 compute).
// LDS: k 2x8 + v 2x8 + p 18 = 50 KB -> 3 blocks/CU (24 waves/CU).
__global__ __launch_bounds__(512) void attn_part_kernel(
    const unsigned short* __restrict__ qkvqk, const unsigned short* __restrict__ vt,
    unsigned short* __restrict__ opart, float* __restrict__ ml) {
  const int Ctab[16] = {0,1,3,6,10,15,21,28,36,45,55,66,78,91,105,120};
  const int f  = blockIdx.x;       // 0..1087
  const int bz = f / 136;
  const int rw = f - bz * 136;
  int s = 0;
  #pragma unroll
  for (int t = 1; t < 16; ++t) if (rw >= Ctab[t]) s = t;
  const int c = rw - Ctab[s];      // 0..s

  __shared__ __align__(16) unsigned short k_lds[2][64 * 64];     // 2x8 KB, swizzled
  __shared__ __align__(16) unsigned short v_lds[2][64 * 64];     // 2x8 KB, swizzled
  __shared__ __align__(16) unsigned short p_lds[2 * 64 * KST];   // 18 KB, padded

  const int tid  = threadIdx.x;
  const int w    = tid >> 6;       // 0..7
  const int grp  = w >> 2;         // 0 = q-tile 2s, 1 = q-tile 2s+1
  const int wq   = w & 3;          // 16-row slice within the 64-row q-tile
  const int lane = tid & 63;
  const int ln   = lane & 15;
  const int quad = lane >> 4;
  const int lsw  = ln & 7;         // read-side swizzle key
  const int bb   = bz * TT;
  const int kbase = c * 128;
  const int qt   = 2 * s + grp;    // this group's q-tile

  // Pre-computed stage addressing: 512 slots per half (1 DMA/thread for K and V).
  // K: slot -> (row = slot>>3, cc = slot&7); data = global chunk cc ^ (row&7).
  // V: slot -> (d   = slot>>3, cc = slot&7); data = global chunk cc ^ (d&7).
  const int slot = w * 64 + lane;
  const int srow = slot >> 3, scc = slot & 7;
  const unsigned short* kgp =
      qkvqk + (size_t)(bb + kbase + srow) * 128 + 64 + ((scc ^ (srow & 7)) << 3);
  const unsigned short* vgp =
      vt + ((size_t)bz * 64 + srow) * TT + kbase + ((scc ^ (srow & 7)) << 3);

  // Q fragments (log2-scaled already); A-layout m=lane&15, k=quad*8+j
  const unsigned short* qrow = qkvqk + (size_t)(bb + qt * 64 + wq * 16 + ln) * 128;
  const s16x8 qf0 = *(const s16x8*)(qrow + quad * 8);
  const s16x8 qf1 = *(const s16x8*)(qrow + 32 + quad * 8);

  s16x8 ones;
  #pragma unroll
  for (int j = 0; j < 8; ++j) ones[j] = (short)0x3F80;  // bf16 1.0

  f32x4 acc_o[4], acc_l;
  #pragma unroll
  for (int i = 0; i < 4; ++i) acc_o[i] = (f32x4){0.f, 0.f, 0.f, 0.f};
  acc_l = (f32x4){0.f, 0.f, 0.f, 0.f};

  unsigned short* pb = p_lds + grp * 64 * KST;   // group-private P buffer
  const int qg = qt * 64 + wq * 16 + quad * 4;

  // stage half 0 (keys kbase..kbase+63)
  gload_lds16(kgp, (void*)(k_lds[0] + (w * 64) * 8));
  gload_lds16(vgp, (void*)(v_lds[0] + (w * 64) * 8));
  __syncthreads();                 // drains vmcnt(0): half 0 staged
  // issue half 1 prefetch (keys kbase+64..kbase+127); lands under ct=0 compute
  gload_lds16(kgp + 64 * 128, (void*)(k_lds[1] + (w * 64) * 8));
  gload_lds16(vgp + 64,       (void*)(v_lds[1] + (w * 64) * 8));

  #pragma unroll
  for (int ct = 0; ct < 2; ++ct) {
    const unsigned short* kb = k_lds[ct];
    const unsigned short* vb = v_lds[ct];
    const int ktg = c * 2 + ct;
    if (ktg <= qt) {               // group 0 skips ct=1 when c==s
      const bool diag = (ktg == qt);
      f32x4 acc_s[4];
      #pragma unroll
      for (int i = 0; i < 4; ++i) acc_s[i] = (f32x4){0.f, 0.f, 0.f, 0.f};
      #pragma unroll
      for (int ns = 0; ns < 4; ++ns) {
        const int krow = ns * 16 + ln;             // local row within the half
        s16x8 kf0 = *(const s16x8*)&kb[krow * 64 + ((quad ^ lsw) << 3)];
        s16x8 kf1 = *(const s16x8*)&kb[krow * 64 + (((4 + quad) ^ lsw) << 3)];
        MFMA(acc_s[ns], qf0, kf0);
        MFMA(acc_s[ns], qf1, kf1);
      }
      #pragma unroll
      for (int r = 0; r < 4; ++r) {
        const int qgr = qg + r;
        #pragma unroll
        for (int ns = 0; ns < 4; ++ns) {
          float sv = acc_s[ns][r];
          if (diag) {
            int kg = ktg * 64 + ns * 16 + ln;
            sv = (kg <= qgr) ? sv : -1e30f;
          }
          pb[(wq * 16 + quad * 4 + r) * KST + ns * 16 + ln] =
              f2bf(__builtin_amdgcn_exp2f(sv));
        }
      }
      #pragma unroll
      for (int kk = 0; kk < 64; kk += 32) {
        s16x8 pf = *(const s16x8*)&pb[(wq * 16 + ln) * KST + kk + quad * 8];
        MFMA(acc_l, pf, ones);
        #pragma unroll
        for (int nt = 0; nt < 4; ++nt) {
          const int d  = nt * 16 + ln;
          const int sc = ((kk >> 3) + quad) ^ lsw;   // 8 chunks/row, xor low 3 bits
          s16x8 vf = *(const s16x8*)&vb[d * 64 + sc * 8];
          MFMA(acc_o[nt], pf, vf);
        }
      }
      asm volatile("" ::: "memory");
    }
    if (ct == 0) __syncthreads();  // drains half-1 loads (issued one compute ago)
  }

  // epilogue: slab base per qt: base(2s)=s(s+1), base(2s+1)=(s+1)^2
  const int base = (qt & 1) ? (s + 1) * (s + 1) : s * (s + 1);
  const size_t slab = (size_t)bz * 272 + base + c;
  unsigned short* op = opart + slab * 4096;
  #pragma unroll
  for (int nt = 0; nt < 4; ++nt)
    #pragma unroll
    for (int r = 0; r < 4; ++r)
      op[(wq * 16 + quad * 4 + r) * 64 + nt * 16 + ln] = f2bf(acc_o[nt][r]);
  if (ln == 0) {
    float* lp = ml + slab * 64;
    #pragma unroll
    for (int r = 0; r < 4; ++r)
      lp[wq * 16 + quad * 4 + r] = acc_l[r];
  }
}

// ---------------- combine: weight-1 merge of <=16 chunks -----------------------------
__global__ __launch_bounds__(256) void attn_combine_kernel(
    const unsigned short* __restrict__ opart, const float* __restrict__ ml,
    float* __restrict__ out) {
  const int qt = blockIdx.x;       // 0..31
  const int bz = blockIdx.y;
  const int g  = qt >> 1;
  const int nch = g + 1;           // chunks per q-tile (1..16)
  const int base = (qt & 1) ? (g + 1) * (g + 1) : g * (g + 1);
  const size_t slab0 = (size_t)bz * 272 + base;

  const int tid = threadIdx.x;
  const int row = tid >> 2;
  const int ds  = (tid & 3) * 16;

  float L = 0.f;
  float acc[16];
  #pragma unroll
  for (int j = 0; j < 16; ++j) acc[j] = 0.f;
  #pragma unroll 4
  for (int ch = 0; ch < nch; ++ch) {
    L += ml[(slab0 + ch) * 64 + row];
    const unsigned short* op = opart + (slab0 + ch) * 4096 + row * 64 + ds;
    i32x4 v0 = *(const i32x4*)(op);
    i32x4 v1 = *(const i32x4*)(op + 8);
    #pragma unroll
    for (int j = 0; j < 4; ++j) {
      unsigned int u0 = (unsigned int)v0[j], u1 = (unsigned int)v1[j];
      acc[j * 2]         += __uint_as_float(u0 << 16);
      acc[j * 2 + 1]     += __uint_as_float(u0 & 0xffff0000u);
      acc[8 + j * 2]     += __uint_as_float(u1 << 16);
      acc[8 + j * 2 + 1] += __uint_as_float(u1 & 0xffff0000u);
    }
  }
  float inv = 1.0f / L;
  float* o = out + ((size_t)bz * TT + qt * 64 + row) * 64 + ds;
  #pragma unroll
  for (int j = 0; j < 16; ++j) o[j] = acc[j] * inv;
}

extern "C" void kernel_launch(void* const* d_in, const int* in_sizes, int n_in,
                              void* d_out, int out_size, void* d_ws, size_t ws_size,
                              hipStream_t stream) {
  const float* x  = (const float*)d_in[0];
  const float* wq = (const float*)d_in[1];
  const float* wk = (const float*)d_in[2];
  const float* wv = (const float*)d_in[3];
  float* out = (float*)d_out;

  char* ws = (char*)d_ws;
  unsigned short* wt    = (unsigned short*)(ws + WS_WT);
  unsigned short* qkvqk = (unsigned short*)(ws + WS_QK);
  unsigned short* vt    = (unsigned short*)(ws + WS_VT);
  unsigned short* opart = (unsigned short*)(ws + WS_OP);
  float*          ml    = (float*)(ws + WS_ML);

  pack_w_kernel<<<(192 * DM + 255) / 256, 256, 0, stream>>>(wq, wk, wv, wt);
  qkv_gemm_kernel<<<NB * TT / 32, 256, 0, stream>>>(x, wt, qkvqk, vt);
  attn_part_kernel<<<NB * 136, 512, 0, stream>>>(qkvqk, vt, opart, ml);
  attn_combine_kernel<<<dim3(32, NB), 256, 0, stream>>>(opart, ml, out);
}

// Round 12
// 130.652 us; speedup vs baseline: 1.0652x; 1.0047x over previous
//
#include <hip/hip_runtime.h>

// B=8, T=2048, D_MODEL=1024, D_HEAD=64, fp32 in/out.
// pack  -> Wt bf16[192][1024]
// gemm  -> qkvqk bf16[16384][128] (Q log2-scaled | K), vT bf16[8][64][2048]
//          R13 gemm (BK=128, 32x192, 512 blocks) — best measured; R15/R16/R17
//          alternatives (BK=64/256, N-split occupancy) all neutral-or-worse.
//          NO setprio here (m190: hurts lockstep-barrier GEMM).
// attn  -> R19: R18 (half-tile K/V prefetch, A/B wave-group split) + T5 setprio(1)
//          around QK and PV MFMA clusters (6 wave-groups/CU at diverse phases ->
//          scheduler favors MFMA-entering waves; learn_hip m191 attn +4-7%).
// combine -> weight-1 merge of <=16 chunks per (b, 64-row q-tile)
#define TT   2048
#define DM   1024
#define DH   64
#define NB   8
#define BK   128   // gemm K-tile (8 barrier-drains)
#define KST  72    // p_lds row stride (elems)

typedef __attribute__((ext_vector_type(4))) float          f32x4;
typedef __attribute__((ext_vector_type(4))) int            i32x4;
typedef __attribute__((ext_vector_type(4))) unsigned short u16x4;
typedef __attribute__((ext_vector_type(8))) short          s16x8;  // bf16x8 frag (4 VGPRs)

__device__ __forceinline__ unsigned short f2bf(float f) {  // RNE fp32->bf16
  unsigned int u = __float_as_uint(f);
  u += 0x7fffu + ((u >> 16) & 1u);
  return (unsigned short)(u >> 16);
}

#define MFMA(acc, a, b) \
  (acc) = __builtin_amdgcn_mfma_f32_16x16x32_bf16((a), (b), (acc), 0, 0, 0)

// Async global->LDS DMA, 16B/lane. LDS dest is wave-uniform base + lane*16.
__device__ __forceinline__ void gload_lds16(const void* g, void* l) {
  __builtin_amdgcn_global_load_lds(
      (const __attribute__((address_space(1))) void*)g,
      (__attribute__((address_space(3))) void*)l, 16, 0, 0);
}

// ws layout (bytes)
#define WS_WT    0u
#define WS_QK    393216u     // 16384*128*2 = 4,194,304
#define WS_VT    4587520u    // 8*64*2048*2 = 2,097,152
#define WS_OP    6684672u    // 8*272*4096*2 = 17,825,792 (bf16 partial O)
#define WS_ML    24510464u   // 8*272*64*4   = 557,056    (f32 l per row)

// ---------------- pack: W_Q|W_K|W_V fp32[1024][64] -> Wt bf16[192][1024] -------------
__global__ __launch_bounds__(256) void pack_w_kernel(
    const float* __restrict__ wq, const float* __restrict__ wk,
    const float* __restrict__ wv, unsigned short* __restrict__ wt) {
  int idx = blockIdx.x * 256 + threadIdx.x;
  if (idx >= 192 * DM) return;
  int n = idx >> 10;
  int k = idx & (DM - 1);
  const float* src = (n < 64) ? wq : ((n < 128) ? wk : wv);
  wt[(size_t)n * DM + k] = f2bf(src[(size_t)k * DH + (n & 63)]);
}

// ---------------- QKV GEMM (m97 structure, BK=128) -----------------------------------
// 512 blocks x 256 thr (2 blocks/CU: LDS 64 KB x 2 = 128 <= 160 KB). Block = 32 rows x
// 192 cols, K-step 128 -> 8 vmcnt-drain barriers. A fp32 + B bf16 staged by
// global_load_lds into XOR-swizzled LDS (reads un-swizzle with ^lsw).
__global__ __launch_bounds__(256) void qkv_gemm_kernel(
    const float* __restrict__ x, const unsigned short* __restrict__ wt,
    unsigned short* __restrict__ qkvqk, unsigned short* __restrict__ vt) {
  __shared__ __align__(16) float          a_lds[32 * BK];    // 16 KB, swizzled chunks
  __shared__ __align__(16) unsigned short b_lds[192 * BK];   // 48 KB, swizzled chunks

  const int tid  = threadIdx.x;
  const int lane = tid & 63;
  const int w    = tid >> 6;
  const int ln   = lane & 15;
  const int quad = lane >> 4;
  const int mw   = w & 1;
  const int nw   = w >> 1;
  const int m0   = blockIdx.x * 32;
  const int n0   = nw * 96;
  const int lsw  = ln & 7;          // read-side swizzle key

  // A: 32 rows x 32 chunks (16B = 4 fp32). 1024 slots, 4 DMAs/wave.
  int agoff[4];
  #pragma unroll
  for (int i = 0; i < 4; ++i) {
    int s = i * 256 + w * 64 + lane;
    int m = s >> 5, cc = s & 31;
    agoff[i] = (m0 + m) * DM + ((cc ^ (m & 7)) << 2);
  }
  // B: 192 rows x 16 chunks (16B = 8 bf16). 3072 slots, 12 DMAs/wave.
  int bgoff[12];
  #pragma unroll
  for (int j = 0; j < 12; ++j) {
    int s = j * 256 + w * 64 + lane;
    int n = s >> 4, cc = s & 15;
    bgoff[j] = n * DM + ((cc ^ (n & 7)) << 3);
  }

  f32x4 acc[6];
  #pragma unroll
  for (int i = 0; i < 6; ++i) acc[i] = (f32x4){0.f, 0.f, 0.f, 0.f};
  union { s16x8 v; unsigned short h[8]; } ap;

  // prologue stage of tile 0
  #pragma unroll
  for (int i = 0; i < 4; ++i)
    gload_lds16(x + agoff[i], (void*)(a_lds + (i * 256 + w * 64) * 4));
  #pragma unroll
  for (int j = 0; j < 12; ++j)
    gload_lds16(wt + bgoff[j], (void*)(b_lds + (j * 256 + w * 64) * 8));

  for (int k0 = 0; k0 < DM; k0 += BK) {
    __syncthreads();               // drains vmcnt(0): staged tile visible
    #pragma unroll
    for (int ks = 0; ks < BK; ks += 32) {
      const int m  = mw * 16 + ln;
      const int c0 = (ks >> 2) + 2 * quad;       // float-chunk of A fragment
      f32x4 v0 = *(const f32x4*)&a_lds[m * BK + ((c0 ^ lsw) << 2)];
      f32x4 v1 = *(const f32x4*)&a_lds[m * BK + (((c0 + 1) ^ lsw) << 2)];
      #pragma unroll
      for (int j = 0; j < 4; ++j) { ap.h[j] = f2bf(v0[j]); ap.h[4 + j] = f2bf(v1[j]); }
      s16x8 af = ap.v;
      const int cb = (ks >> 3) + quad;           // bf16-chunk of B fragment
      #pragma unroll
      for (int nt = 0; nt < 6; ++nt) {
        int n = n0 + nt * 16 + ln;
        s16x8 bf = *(const s16x8*)&b_lds[n * BK + ((cb ^ lsw) << 3)];
        MFMA(acc[nt], af, bf);
      }
    }
    __syncthreads();               // all waves done reading before re-stage
    if (k0 + BK < DM) {
      const int kn = k0 + BK;
      #pragma unroll
      for (int i = 0; i < 4; ++i)
        gload_lds16(x + agoff[i] + kn, (void*)(a_lds + (i * 256 + w * 64) * 4));
      #pragma unroll
      for (int j = 0; j < 12; ++j)
        gload_lds16(wt + bgoff[j] + kn, (void*)(b_lds + (j * 256 + w * 64) * 8));
    }
  }

  const float QS = 0.18033688011112042f;  // (1/8) * log2(e)
  const int mm0 = m0 + mw * 16;
  const int bz  = mm0 >> 11;
  const int tb  = (mm0 & 2047) + quad * 4;
  #pragma unroll
  for (int nt = 0; nt < 6; ++nt) {
    const int ncol = n0 + nt * 16 + ln;
    if (ncol < 128) {                     // Q (scaled) | K -> qkvqk
      const float sc = (ncol < 64) ? QS : 1.0f;
      #pragma unroll
      for (int r = 0; r < 4; ++r) {
        int row = mm0 + quad * 4 + r;     // C/D: row = quad*4+reg, col = lane&15
        qkvqk[(size_t)row * 128 + ncol] = f2bf(acc[nt][r] * sc);
      }
    } else {                              // V -> vT[b][d][t]
      int d = ncol - 128;
      u16x4 h;
      #pragma unroll
      for (int r = 0; r < 4; ++r) h[r] = f2bf(acc[nt][r]);
      *(u16x4*)(vt + ((size_t)bz * 64 + d) * TT + tb) = h;
    }
  }
}

// ---------------- attn partial: 128-row q-supertile x 128-key chunk (R19) ------------
// Per b: supertile s (0..15), chunk c (0..s): Ctab[s]=s(s+1)/2, 136 blocks/b, grid 1088.
// 512 threads: waves 0-3 -> q-tile 2s, waves 4-7 -> q-tile 2s+1, concurrent.
// K/V staged in TWO 64-key halves: stage(0) -> drain -> issue stage(1) ->
// compute ct=0 -> drain -> compute ct=1 (half-1 staging hidden under ct=0 compute).
// T5: setprio(1) around QK and PV MFMA clusters (wave-group phase diversity).
// LDS: k 2x8 + v 2x8 + p 18 = 50 KB -> 3 blocks/CU (24 waves/CU).
__global__ __launch_bounds__(512) void attn_part_kernel(
    const unsigned short* __restrict__ qkvqk, const unsigned short* __restrict__ vt,
    unsigned short* __restrict__ opart, float* __restrict__ ml) {
  const int Ctab[16] = {0,1,3,6,10,15,21,28,36,45,55,66,78,91,105,120};
  const int f  = blockIdx.x;       // 0..1087
  const int bz = f / 136;
  const int rw = f - bz * 136;
  int s = 0;
  #pragma unroll
  for (int t = 1; t < 16; ++t) if (rw >= Ctab[t]) s = t;
  const int c = rw - Ctab[s];      // 0..s

  __shared__ __align__(16) unsigned short k_lds[2][64 * 64];     // 2x8 KB, swizzled
  __shared__ __align__(16) unsigned short v_lds[2][64 * 64];     // 2x8 KB, swizzled
  __shared__ __align__(16) unsigned short p_lds[2 * 64 * KST];   // 18 KB, padded

  const int tid  = threadIdx.x;
  const int w    = tid >> 6;       // 0..7
  const int grp  = w >> 2;         // 0 = q-tile 2s, 1 = q-tile 2s+1
  const int wq   = w & 3;          // 16-row slice within the 64-row q-tile
  const int lane = tid & 63;
  const int ln   = lane & 15;
  const int quad = lane >> 4;
  const int lsw  = ln & 7;         // read-side swizzle key
  const int bb   = bz * TT;
  const int kbase = c * 128;
  const int qt   = 2 * s + grp;    // this group's q-tile

  // Pre-computed stage addressing: 512 slots per half (1 DMA/thread for K and V).
  // K: slot -> (row = slot>>3, cc = slot&7); data = global chunk cc ^ (row&7).
  // V: slot -> (d   = slot>>3, cc = slot&7); data = global chunk cc ^ (d&7).
  const int slot = w * 64 + lane;
  const int srow = slot >> 3, scc = slot & 7;
  const unsigned short* kgp =
      qkvqk + (size_t)(bb + kbase + srow) * 128 + 64 + ((scc ^ (srow & 7)) << 3);
  const unsigned short* vgp =
      vt + ((size_t)bz * 64 + srow) * TT + kbase + ((scc ^ (srow & 7)) << 3);

  // Q fragments (log2-scaled already); A-layout m=lane&15, k=quad*8+j
  const unsigned short* qrow = qkvqk + (size_t)(bb + qt * 64 + wq * 16 + ln) * 128;
  const s16x8 qf0 = *(const s16x8*)(qrow + quad * 8);
  const s16x8 qf1 = *(const s16x8*)(qrow + 32 + quad * 8);

  s16x8 ones;
  #pragma unroll
  for (int j = 0; j < 8; ++j) ones[j] = (short)0x3F80;  // bf16 1.0

  f32x4 acc_o[4], acc_l;
  #pragma unroll
  for (int i = 0; i < 4; ++i) acc_o[i] = (f32x4){0.f, 0.f, 0.f, 0.f};
  acc_l = (f32x4){0.f, 0.f, 0.f, 0.f};

  unsigned short* pb = p_lds + grp * 64 * KST;   // group-private P buffer
  const int qg = qt * 64 + wq * 16 + quad * 4;

  // stage half 0 (keys kbase..kbase+63)
  gload_lds16(kgp, (void*)(k_lds[0] + (w * 64) * 8));
  gload_lds16(vgp, (void*)(v_lds[0] + (w * 64) * 8));
  __syncthreads();                 // drains vmcnt(0): half 0 staged
  // issue half 1 prefetch (keys kbase+64..kbase+127); lands under ct=0 compute
  gload_lds16(kgp + 64 * 128, (void*)(k_lds[1] + (w * 64) * 8));
  gload_lds16(vgp + 64,       (void*)(v_lds[1] + (w * 64) * 8));

  #pragma unroll
  for (int ct = 0; ct < 2; ++ct) {
    const unsigned short* kb = k_lds[ct];
    const unsigned short* vb = v_lds[ct];
    const int ktg = c * 2 + ct;
    if (ktg <= qt) {               // group 0 skips ct=1 when c==s
      const bool diag = (ktg == qt);
      f32x4 acc_s[4];
      #pragma unroll
      for (int i = 0; i < 4; ++i) acc_s[i] = (f32x4){0.f, 0.f, 0.f, 0.f};
      __builtin_amdgcn_s_setprio(1);           // T5: favor QK MFMA cluster
      #pragma unroll
      for (int ns = 0; ns < 4; ++ns) {
        const int krow = ns * 16 + ln;             // local row within the half
        s16x8 kf0 = *(const s16x8*)&kb[krow * 64 + ((quad ^ lsw) << 3)];
        s16x8 kf1 = *(const s16x8*)&kb[krow * 64 + (((4 + quad) ^ lsw) << 3)];
        MFMA(acc_s[ns], qf0, kf0);
        MFMA(acc_s[ns], qf1, kf1);
      }
      __builtin_amdgcn_s_setprio(0);
      #pragma unroll
      for (int r = 0; r < 4; ++r) {
        const int qgr = qg + r;
        #pragma unroll
        for (int ns = 0; ns < 4; ++ns) {
          float sv = acc_s[ns][r];
          if (diag) {
            int kg = ktg * 64 + ns * 16 + ln;
            sv = (kg <= qgr) ? sv : -1e30f;
          }
          pb[(wq * 16 + quad * 4 + r) * KST + ns * 16 + ln] =
              f2bf(__builtin_amdgcn_exp2f(sv));
        }
      }
      __builtin_amdgcn_s_setprio(1);           // T5: favor PV MFMA cluster
      #pragma unroll
      for (int kk = 0; kk < 64; kk += 32) {
        s16x8 pf = *(const s16x8*)&pb[(wq * 16 + ln) * KST + kk + quad * 8];
        MFMA(acc_l, pf, ones);
        #pragma unroll
        for (int nt = 0; nt < 4; ++nt) {
          const int d  = nt * 16 + ln;
          const int sc = ((kk >> 3) + quad) ^ lsw;   // 8 chunks/row, xor low 3 bits
          s16x8 vf = *(const s16x8*)&vb[d * 64 + sc * 8];
          MFMA(acc_o[nt], pf, vf);
        }
      }
      __builtin_amdgcn_s_setprio(0);
      asm volatile("" ::: "memory");
    }
    if (ct == 0) __syncthreads();  // drains half-1 loads (issued one compute ago)
  }

  // epilogue: slab base per qt: base(2s)=s(s+1), base(2s+1)=(s+1)^2
  const int base = (qt & 1) ? (s + 1) * (s + 1) : s * (s + 1);
  const size_t slab = (size_t)bz * 272 + base + c;
  unsigned short* op = opart + slab * 4096;
  #pragma unroll
  for (int nt = 0; nt < 4; ++nt)
    #pragma unroll
    for (int r = 0; r < 4; ++r)
      op[(wq * 16 + quad * 4 + r) * 64 + nt * 16 + ln] = f2bf(acc_o[nt][r]);
  if (ln == 0) {
    float* lp = ml + slab * 64;
    #pragma unroll
    for (int r = 0; r < 4; ++r)
      lp[wq * 16 + quad * 4 + r] = acc_l[r];
  }
}

// ---------------- combine: weight-1 merge of <=16 chunks -----------------------------
__global__ __launch_bounds__(256) void attn_combine_kernel(
    const unsigned short* __restrict__ opart, const float* __restrict__ ml,
    float* __restrict__ out) {
  const int qt = blockIdx.x;       // 0..31
  const int bz = blockIdx.y;
  const int g  = qt >> 1;
  const int nch = g + 1;           // chunks per q-tile (1..16)
  const int base = (qt & 1) ? (g + 1) * (g + 1) : g * (g + 1);
  const size_t slab0 = (size_t)bz * 272 + base;

  const int tid = threadIdx.x;
  const int row = tid >> 2;
  const int ds  = (tid & 3) * 16;

  float L = 0.f;
  float acc[16];
  #pragma unroll
  for (int j = 0; j < 16; ++j) acc[j] = 0.f;
  #pragma unroll 4
  for (int ch = 0; ch < nch; ++ch) {
    L += ml[(slab0 + ch) * 64 + row];
    const unsigned short* op = opart + (slab0 + ch) * 4096 + row * 64 + ds;
    i32x4 v0 = *(const i32x4*)(op);
    i32x4 v1 = *(const i32x4*)(op + 8);
    #pragma unroll
    for (int j = 0; j < 4; ++j) {
      unsigned int u0 = (unsigned int)v0[j], u1 = (unsigned int)v1[j];
      acc[j * 2]         += __uint_as_float(u0 << 16);
      acc[j * 2 + 1]     += __uint_as_float(u0 & 0xffff0000u);
      acc[8 + j * 2]     += __uint_as_float(u1 << 16);
      acc[8 + j * 2 + 1] += __uint_as_float(u1 & 0xffff0000u);
    }
  }
  float inv = 1.0f / L;
  float* o = out + ((size_t)bz * TT + qt * 64 + row) * 64 + ds;
  #pragma unroll
  for (int j = 0; j < 16; ++j) o[j] = acc[j] * inv;
}

extern "C" void kernel_launch(void* const* d_in, const int* in_sizes, int n_in,
                              void* d_out, int out_size, void* d_ws, size_t ws_size,
                              hipStream_t stream) {
  const float* x  = (const float*)d_in[0];
  const float* wq = (const float*)d_in[1];
  const float* wk = (const float*)d_in[2];
  const float* wv = (const float*)d_in[3];
  float* out = (float*)d_out;

  char* ws = (char*)d_ws;
  unsigned short* wt    = (unsigned short*)(ws + WS_WT);
  unsigned short* qkvqk = (unsigned short*)(ws + WS_QK);
  unsigned short* vt    = (unsigned short*)(ws + WS_VT);
  unsigned short* opart = (unsigned short*)(ws + WS_OP);
  float*          ml    = (float*)(ws + WS_ML);

  pack_w_kernel<<<(192 * DM + 255) / 256, 256, 0, stream>>>(wq, wk, wv, wt);
  qkv_gemm_kernel<<<NB * TT / 32, 256, 0, stream>>>(x, wt, qkvqk, vt);
  attn_part_kernel<<<NB * 136, 512, 0, stream>>>(qkvqk, vt, opart, ml);
  attn_combine_kernel<<<dim3(32, NB), 256, 0, stream>>>(opart, ml, out);
}